// Round 1
// baseline (812.779 us; speedup 1.0000x reference)
//
#include <hip/hip_runtime.h>
#include <cstdint>
#include <cstddef>

// ---------------- problem constants ----------------
#define HD    1024
#define FD    4096
#define NE    8
#define NTOK  4096            // 2*2048
#define CAP   1280            // ceil(2*1.25*4096/8)
#define NSLOT (NE*CAP)        // 10240 expert slots
#define TOTSLOT (NSLOT+NTOK)  // + shared rows

typedef float    f32x4 __attribute__((ext_vector_type(4)));
typedef float    f32x2 __attribute__((ext_vector_type(2)));
typedef _Float16 f16x8 __attribute__((ext_vector_type(8)));
typedef _Float16 f16x4 __attribute__((ext_vector_type(4)));

typedef __attribute__((address_space(3))) unsigned int as3_u32;
typedef __attribute__((address_space(1))) unsigned int as1_u32;

// async global->LDS, 16B/lane. LDS dest is wave-uniform base + lane*16 (m104/m108);
// GLOBAL side is fully per-lane -> implements the expert-token gather for free.
__device__ __forceinline__ void load_lds16(const _Float16* g, _Float16* l) {
  __builtin_amdgcn_global_load_lds((const as1_u32*)g, (as3_u32*)l, 16, 0, 0);
}

// ---------------- 1) weight convert + transpose (fp32 [R][C] -> fp16 [C][R]) ----
// 18 tensors-of-1024-tiles: 8x w1, 8x w2, sw1, sw2. 64x64 tiles via LDS.
__global__ __launch_bounds__(256) void transpose_cvt(
    const float* __restrict__ w1, const float* __restrict__ w2,
    const float* __restrict__ sw1, const float* __restrict__ sw2,
    _Float16* __restrict__ w1t, _Float16* __restrict__ w2t,
    _Float16* __restrict__ sw1t, _Float16* __restrict__ sw2t)
{
  int bx = blockIdx.x;
  int tt = bx >> 10;          // tensor id 0..17 (each tensor = exactly 1024 tiles)
  int tile = bx & 1023;
  const float* src; _Float16* dst; int R, Cc;
  if (tt < 8)       { src = w1 + (size_t)tt*HD*FD;      dst = w1t + (size_t)tt*FD*HD; R = HD; Cc = FD; }
  else if (tt < 16) { int e = tt-8; src = w2 + (size_t)e*FD*HD; dst = w2t + (size_t)e*HD*FD; R = FD; Cc = HD; }
  else if (tt == 16){ src = sw1; dst = sw1t; R = HD; Cc = FD; }
  else              { src = sw2; dst = sw2t; R = FD; Cc = HD; }
  int shift = (Cc == FD) ? 6 : 4;       // tiles_c = Cc/64 is a power of 2
  int tc = tile & ((1 << shift) - 1);
  int tr = tile >> shift;

  __shared__ float t[64][65];
  int tid = threadIdx.x;
  #pragma unroll
  for (int it = 0; it < 4; ++it) {
    int q = tid + it*256;               // 1024 float4 chunks
    int row = q >> 4, c4 = q & 15;
    f32x4 v = *(const f32x4*)(src + (size_t)(tr*64+row)*Cc + tc*64 + c4*4);
    t[row][c4*4+0] = v[0]; t[row][c4*4+1] = v[1];
    t[row][c4*4+2] = v[2]; t[row][c4*4+3] = v[3];
  }
  __syncthreads();
  #pragma unroll
  for (int it = 0; it < 2; ++it) {
    int q = tid + it*256;               // 512 8-half chunks
    int orow = q >> 3, oc8 = q & 7;
    f16x8 h;
    #pragma unroll
    for (int j = 0; j < 8; ++j) h[j] = (_Float16)t[oc8*8+j][orow];
    *(f16x8*)(dst + (size_t)(tc*64+orow)*R + tr*64 + oc8*8) = h;
  }
}

// ---------------- 2) x fp32 -> fp16 ----------------
__global__ __launch_bounds__(256) void convert_x(const float* __restrict__ x,
                                                 _Float16* __restrict__ x16)
{
  size_t i = ((size_t)blockIdx.x*256 + threadIdx.x) * 4;
  f32x4 v = *(const f32x4*)(x + i);
  f16x4 h; h[0]=(_Float16)v[0]; h[1]=(_Float16)v[1]; h[2]=(_Float16)v[2]; h[3]=(_Float16)v[3];
  *(f16x4*)(x16 + i) = h;
}

// ---------------- 3) router logits, fp64 accumulation (tie-flip insurance) -----
__global__ __launch_bounds__(256) void router_kernel(const float* __restrict__ x,
    const float* __restrict__ rw, double* __restrict__ logits)
{
  int w = threadIdx.x >> 6, lane = threadIdx.x & 63;
  int tok = blockIdx.x*4 + w;
  const float* xr = x + (size_t)tok * HD;
  double acc[8] = {0,0,0,0,0,0,0,0};
  #pragma unroll
  for (int it = 0; it < 4; ++it) {
    int h = it*256 + lane*4;
    f32x4 xv = *(const f32x4*)(xr + h);
    #pragma unroll
    for (int j = 0; j < 4; ++j) {
      const float* wr = rw + (size_t)(h+j)*NE;
      f32x4 w0 = *(const f32x4*)wr;
      f32x4 w1v = *(const f32x4*)(wr+4);
      double xd = (double)xv[j];
      acc[0] += xd*(double)w0[0];  acc[1] += xd*(double)w0[1];
      acc[2] += xd*(double)w0[2];  acc[3] += xd*(double)w0[3];
      acc[4] += xd*(double)w1v[0]; acc[5] += xd*(double)w1v[1];
      acc[6] += xd*(double)w1v[2]; acc[7] += xd*(double)w1v[3];
    }
  }
  #pragma unroll
  for (int d = 1; d < 64; d <<= 1) {
    #pragma unroll
    for (int e = 0; e < 8; ++e) acc[e] += __shfl_xor(acc[e], d, 64);
  }
  if (lane == 0) {
    double* lp = logits + (size_t)tok*NE;
    #pragma unroll
    for (int e = 0; e < 8; ++e) lp[e] = acc[e];
  }
}

// ---------------- 4) top-2 gating, single block (token-order cumsums) ----------
__device__ __forceinline__ int wave_incl_scan(int v, int lane) {
  #pragma unroll
  for (int d = 1; d < 64; d <<= 1) {
    int u = __shfl_up(v, d, 64);
    if (lane >= d) v += u;
  }
  return v;
}

__global__ __launch_bounds__(256) void gating_kernel(const double* __restrict__ logits,
    int4* __restrict__ meta_i, f32x2* __restrict__ meta_f,
    int* __restrict__ slot_src, int* __restrict__ rows_dev)
{
  __shared__ unsigned char sE1[NTOK], sE2[NTOK];
  __shared__ float sG1[NTOK], sG2[NTOK];
  __shared__ int wsum1[8][4], wsum2[8][4];
  int tid = threadIdx.x, lane = tid & 63, w = tid >> 6;

  for (int i = tid; i < NSLOT; i += 256) slot_src[i] = 0;   // ws is poisoned; unused slots -> token 0

  int lc1[8] = {0,0,0,0,0,0,0,0}, lc2[8] = {0,0,0,0,0,0,0,0};
  #pragma unroll 1
  for (int i = 0; i < 16; ++i) {
    int n = tid*16 + i;
    const double* lp = logits + (size_t)n*NE;
    double l[8];
    #pragma unroll
    for (int e = 0; e < 8; ++e) l[e] = lp[e];
    int e1 = 0; double b1v = l[0];
    #pragma unroll
    for (int e = 1; e < 8; ++e) if (l[e] > b1v) { b1v = l[e]; e1 = e; }  // first-occurrence argmax
    double s = 0.0;
    #pragma unroll
    for (int e = 0; e < 8; ++e) s += exp(l[e] - b1v);
    int e2 = 0; double b2v = -1e300;
    #pragma unroll
    for (int e = 0; e < 8; ++e) if (e != e1 && l[e] > b2v) { b2v = l[e]; e2 = e; }
    sE1[n] = (unsigned char)e1; sE2[n] = (unsigned char)e2;
    sG1[n] = (float)(1.0 / s);
    sG2[n] = (float)(exp(b2v - b1v) / s);
    #pragma unroll
    for (int e = 0; e < 8; ++e) { lc1[e] += (e==e1); lc2[e] += (e==e2); }
  }
  int inc1[8], inc2[8];
  #pragma unroll
  for (int e = 0; e < 8; ++e) {
    inc1[e] = wave_incl_scan(lc1[e], lane);
    inc2[e] = wave_incl_scan(lc2[e], lane);
    if (lane == 63) { wsum1[e][w] = inc1[e]; wsum2[e][w] = inc2[e]; }
  }
  __syncthreads();
  int off1[8], off2[8], tot2[8], kept1[8];
  #pragma unroll
  for (int e = 0; e < 8; ++e) {
    int wp1=0, wp2=0, t1=0, t2=0;
    #pragma unroll
    for (int j = 0; j < 4; ++j) {
      int v1 = wsum1[e][j], v2 = wsum2[e][j];
      if (j < w) { wp1 += v1; wp2 += v2; }
      t1 += v1; t2 += v2;
    }
    off1[e] = inc1[e] - lc1[e] + wp1;
    off2[e] = inc2[e] - lc2[e] + wp2;
    tot2[e] = t2;
    kept1[e] = min(t1, CAP);          // = sum(mask1) after capacity drop
  }
  int r1[8], r2[8];
  #pragma unroll
  for (int e = 0; e < 8; ++e) { r1[e] = off1[e]; r2[e] = off2[e]; }
  #pragma unroll 1
  for (int i = 0; i < 16; ++i) {
    int n = tid*16 + i;
    int e1 = sE1[n], e2 = sE2[n];
    int p1 = 0, p2 = 0, k1off = 0;
    #pragma unroll
    for (int e = 0; e < 8; ++e) {
      if (e == e1) { p1 = r1[e]; r1[e] = p1 + 1; }
      if (e == e2) { p2 = r2[e]; r2[e] = p2 + 1; k1off = kept1[e]; }
    }
    int loc1 = (p1 < CAP) ? p1 : -1;
    int pp2 = p2 + k1off;
    int loc2 = (pp2 < CAP) ? pp2 : -1;
    float gg1 = (loc1 >= 0) ? sG1[n] : 0.0f;
    float gg2 = (loc2 >= 0) ? sG2[n] : 0.0f;
    float denom = fmaxf(gg1 + gg2, 1.1920929e-07f);  // finfo(f32).eps
    meta_i[n] = make_int4(e1, loc1, e2, loc2);
    f32x2 mf; mf[0] = gg1/denom; mf[1] = gg2/denom;
    meta_f[n] = mf;
    if (loc1 >= 0) slot_src[e1*CAP + loc1] = n;
    if (loc2 >= 0) slot_src[e2*CAP + loc2] = n;
  }
  if (tid < 8) {
    int rr = 0;
    #pragma unroll
    for (int e = 0; e < 8; ++e) if (e == tid) rr = min(kept1[e] + tot2[e], CAP);
    rows_dev[tid] = rr;     // occupied slots are contiguous [0, rows)
  }
}

// ---------------- 5/6) grouped GEMM, m97 structure, f16 MFMA --------------------
// 128x128 tile, BK=64, 4 waves (2x2), 16x16x32 f16 MFMA, 4x4 acc tiles/wave.
// Groups: 0..7 experts (A gathered via slot_src), 8 = shared (A = rows directly).
template<int K, bool G1>
__global__ __launch_bounds__(256) void gemm_kernel(
    const _Float16* __restrict__ A0,     // x16 (G1) or mid16 (G2), row stride K
    const _Float16* __restrict__ Wexp,   // [E][NOUT][K] transposed weights
    const _Float16* __restrict__ Wshd,   // [NOUT][K]
    const float* __restrict__ BiasE,     // [E][NOUT]
    const float* __restrict__ BiasS,     // [NOUT]
    _Float16* __restrict__ Out,          // [TOTSLOT][NOUT]
    const int* __restrict__ slot_src,
    const int* __restrict__ rows_dev,
    int NOUT)
{
  int rt = blockIdx.y;
  int g, tile;
  if (rt < 80) { g = rt / 10; tile = rt % 10; } else { g = 8; tile = rt - 80; }
  int rows = (g < 8) ? rows_dev[g] : NTOK;
  if (tile * 128 >= rows) return;
  int slot_base = (g < 8) ? g * CAP : NSLOT;
  const _Float16* Bw = (g < 8) ? (Wexp + (size_t)g * NOUT * K) : Wshd;
  const float* bias = (g < 8) ? (BiasE + g * NOUT) : BiasS;
  int n0 = blockIdx.x * 128;

  __shared__ _Float16 Ash[128*64];   // [row][64k], unpadded (global_load_lds layout)
  __shared__ _Float16 Bsh[128*64];   // [ncol][64k]

  int tid = threadIdx.x, lane = tid & 63, w = tid >> 6;
  int wm = w & 1, wn = w >> 1;

  const _Float16* aptr[4];
  const _Float16* bptr[4];
  #pragma unroll
  for (int i = 0; i < 4; ++i) {
    int r = (w*4 + i)*8 + (lane >> 3);
    int rg = tile*128 + r;
    size_t arow;
    if (G1) arow = (g < 8) ? (size_t)slot_src[g*CAP + rg] : (size_t)rg;
    else    arow = (size_t)(slot_base + rg);
    aptr[i] = A0 + arow * (size_t)K + (lane & 7)*8;
    bptr[i] = Bw + (size_t)(n0 + r) * K + (lane & 7)*8;
  }

  f32x4 acc[4][4];
  #pragma unroll
  for (int mi = 0; mi < 4; ++mi)
    #pragma unroll
    for (int ni = 0; ni < 4; ++ni)
      acc[mi][ni] = (f32x4)0.0f;

  for (int k0 = 0; k0 < K; k0 += 64) {
    #pragma unroll
    for (int i = 0; i < 4; ++i) load_lds16(aptr[i] + k0, &Ash[(w*4+i)*512]);
    #pragma unroll
    for (int i = 0; i < 4; ++i) load_lds16(bptr[i] + k0, &Bsh[(w*4+i)*512]);
    __syncthreads();
    #pragma unroll
    for (int ks = 0; ks < 2; ++ks) {
      f16x8 af[4], bf[4];
      #pragma unroll
      for (int mi = 0; mi < 4; ++mi)
        af[mi] = *(const f16x8*)&Ash[(wm*64 + mi*16 + (lane&15))*64 + ks*32 + (lane>>4)*8];
      #pragma unroll
      for (int ni = 0; ni < 4; ++ni)
        bf[ni] = *(const f16x8*)&Bsh[(wn*64 + ni*16 + (lane&15))*64 + ks*32 + (lane>>4)*8];
      #pragma unroll
      for (int mi = 0; mi < 4; ++mi)
        #pragma unroll
        for (int ni = 0; ni < 4; ++ni)
          acc[mi][ni] = __builtin_amdgcn_mfma_f32_16x16x32_f16(af[mi], bf[ni], acc[mi][ni], 0, 0, 0);
    }
    __syncthreads();
  }

  // epilogue: C/D layout col=lane&15, row=(lane>>4)*4+reg  (m89-corrected)
  #pragma unroll
  for (int mi = 0; mi < 4; ++mi) {
    #pragma unroll
    for (int r = 0; r < 4; ++r) {
      int m = wm*64 + mi*16 + (lane>>4)*4 + r;
      int rg = tile*128 + m;
      if (rg < rows) {
        size_t orow = (size_t)(slot_base + rg);
        #pragma unroll
        for (int ni = 0; ni < 4; ++ni) {
          int n = n0 + wn*64 + ni*16 + (lane & 15);
          float v = acc[mi][ni][r] + bias[n];
          if (G1) v = v / (1.0f + __expf(-v));   // SiLU
          Out[orow * (size_t)NOUT + n] = (_Float16)v;
        }
      }
    }
  }
}

// ---------------- 7) combine: y = g1*e1out + g2*e2out + 0.1*shared -------------
__global__ __launch_bounds__(256) void combine_kernel(const int4* __restrict__ meta_i,
    const f32x2* __restrict__ meta_f, const _Float16* __restrict__ out16,
    float* __restrict__ out)
{
  int n = blockIdx.x;
  int h = threadIdx.x * 4;
  int4 mi = meta_i[n];
  f32x2 mf = meta_f[n];
  f16x4 sv = *(const f16x4*)(out16 + (size_t)(NSLOT + n)*HD + h);
  f32x4 y;
  #pragma unroll
  for (int j = 0; j < 4; ++j) y[j] = 0.1f * (float)sv[j];
  if (mi.y >= 0) {
    f16x4 v = *(const f16x4*)(out16 + (size_t)(mi.x*CAP + mi.y)*HD + h);
    #pragma unroll
    for (int j = 0; j < 4; ++j) y[j] += mf[0] * (float)v[j];
  }
  if (mi.w >= 0) {
    f16x4 v = *(const f16x4*)(out16 + (size_t)(mi.z*CAP + mi.w)*HD + h);
    #pragma unroll
    for (int j = 0; j < 4; ++j) y[j] += mf[1] * (float)v[j];
  }
  *(f32x4*)(out + (size_t)n*HD + h) = y;
}

__global__ void fill_sentinel(float* out, int nelem) {
  int i = blockIdx.x*256 + threadIdx.x;
  if (i < nelem) out[i] = 12345.0f;   // distinctive: means ws_size was too small
}

// ---------------- host ----------------
extern "C" void kernel_launch(void* const* d_in, const int* in_sizes, int n_in,
                              void* d_out, int out_size, void* d_ws, size_t ws_size,
                              hipStream_t stream) {
  const float* x   = (const float*)d_in[0];
  const float* rw  = (const float*)d_in[1];
  const float* w1  = (const float*)d_in[2];
  const float* b1  = (const float*)d_in[3];
  const float* w2  = (const float*)d_in[4];
  const float* b2  = (const float*)d_in[5];
  const float* sw1 = (const float*)d_in[6];
  const float* sb1 = (const float*)d_in[7];
  const float* sw2 = (const float*)d_in[8];
  const float* sb2 = (const float*)d_in[9];
  float* out = (float*)d_out;

  char* p = (char*)d_ws;
  auto alloc = [&](size_t bytes) { char* r = p; p += (bytes + 255) & ~(size_t)255; return r; };
  _Float16* x16  = (_Float16*)alloc((size_t)NTOK*HD*2);
  _Float16* w1t  = (_Float16*)alloc((size_t)NE*FD*HD*2);
  _Float16* w2t  = (_Float16*)alloc((size_t)NE*HD*FD*2);
  _Float16* sw1t = (_Float16*)alloc((size_t)FD*HD*2);
  _Float16* sw2t = (_Float16*)alloc((size_t)HD*FD*2);
  _Float16* mid  = (_Float16*)alloc((size_t)TOTSLOT*FD*2);
  _Float16* o16  = (_Float16*)alloc((size_t)TOTSLOT*HD*2);
  double* logits = (double*)alloc((size_t)NTOK*NE*8);
  int4*   meta_i = (int4*)alloc((size_t)NTOK*16);
  f32x2*  meta_f = (f32x2*)alloc((size_t)NTOK*8);
  int* slot_src  = (int*)alloc((size_t)NSLOT*4);
  int* rows_dev  = (int*)alloc(64);
  size_t need = (size_t)(p - (char*)d_ws);
  if (need > ws_size) {
    fill_sentinel<<<(out_size+255)/256, 256, 0, stream>>>(out, out_size);
    return;
  }

  transpose_cvt<<<18*1024, 256, 0, stream>>>(w1, w2, sw1, sw2, w1t, w2t, sw1t, sw2t);
  convert_x<<<NTOK*HD/1024, 256, 0, stream>>>(x, x16);
  router_kernel<<<NTOK/4, 256, 0, stream>>>(x, rw, logits);
  gating_kernel<<<1, 256, 0, stream>>>(logits, meta_i, meta_f, slot_src, rows_dev);
  gemm_kernel<HD, true><<<dim3(FD/128, 112), 256, 0, stream>>>(
      x16, w1t, sw1t, b1, sb1, mid, slot_src, rows_dev, FD);
  gemm_kernel<FD, false><<<dim3(HD/128, 112), 256, 0, stream>>>(
      mid, w2t, sw2t, b2, sb2, o16, slot_src, rows_dev, HD);
  combine_kernel<<<NTOK, 256, 0, stream>>>(meta_i, meta_f, o16, out);
}

// Round 2
// 762.479 us; speedup vs baseline: 1.0660x; 1.0660x over previous
//
#include <hip/hip_runtime.h>
#include <cstdint>
#include <cstddef>

// ---------------- problem constants ----------------
#define HD    1024
#define FD    4096
#define NE    8
#define NTOK  4096            // 2*2048
#define CAP   1280            // ceil(2*1.25*4096/8)
#define NSLOT (NE*CAP)        // 10240 expert slots
#define TOTSLOT (NSLOT+NTOK)  // + shared rows

typedef float    f32x4 __attribute__((ext_vector_type(4)));
typedef float    f32x2 __attribute__((ext_vector_type(2)));
typedef _Float16 f16x8 __attribute__((ext_vector_type(8)));
typedef _Float16 f16x4 __attribute__((ext_vector_type(4)));

typedef __attribute__((address_space(3))) unsigned int as3_u32;
typedef __attribute__((address_space(1))) unsigned int as1_u32;

// async global->LDS, 16B/lane. LDS dest is wave-uniform base + lane*16 (m104/m108);
// GLOBAL side is fully per-lane -> implements the expert-token gather for free.
__device__ __forceinline__ void load_lds16(const _Float16* g, _Float16* l) {
  __builtin_amdgcn_global_load_lds((const as1_u32*)g, (as3_u32*)l, 16, 0, 0);
}

// ---------------- 1) weight convert + transpose (fp32 [R][C] -> fp16 [C][R]) ----
__global__ __launch_bounds__(256) void transpose_cvt(
    const float* __restrict__ w1, const float* __restrict__ w2,
    const float* __restrict__ sw1, const float* __restrict__ sw2,
    _Float16* __restrict__ w1t, _Float16* __restrict__ w2t,
    _Float16* __restrict__ sw1t, _Float16* __restrict__ sw2t)
{
  int bx = blockIdx.x;
  int tt = bx >> 10;          // tensor id 0..17 (each tensor = exactly 1024 tiles)
  int tile = bx & 1023;
  const float* src; _Float16* dst; int R, Cc;
  if (tt < 8)       { src = w1 + (size_t)tt*HD*FD;      dst = w1t + (size_t)tt*FD*HD; R = HD; Cc = FD; }
  else if (tt < 16) { int e = tt-8; src = w2 + (size_t)e*FD*HD; dst = w2t + (size_t)e*HD*FD; R = FD; Cc = HD; }
  else if (tt == 16){ src = sw1; dst = sw1t; R = HD; Cc = FD; }
  else              { src = sw2; dst = sw2t; R = FD; Cc = HD; }
  int shift = (Cc == FD) ? 6 : 4;       // tiles_c = Cc/64 is a power of 2
  int tc = tile & ((1 << shift) - 1);
  int tr = tile >> shift;

  __shared__ float t[64][65];
  int tid = threadIdx.x;
  #pragma unroll
  for (int it = 0; it < 4; ++it) {
    int q = tid + it*256;               // 1024 float4 chunks
    int row = q >> 4, c4 = q & 15;
    f32x4 v = *(const f32x4*)(src + (size_t)(tr*64+row)*Cc + tc*64 + c4*4);
    t[row][c4*4+0] = v[0]; t[row][c4*4+1] = v[1];
    t[row][c4*4+2] = v[2]; t[row][c4*4+3] = v[3];
  }
  __syncthreads();
  #pragma unroll
  for (int it = 0; it < 2; ++it) {
    int q = tid + it*256;               // 512 8-half chunks
    int orow = q >> 3, oc8 = q & 7;
    f16x8 h;
    #pragma unroll
    for (int j = 0; j < 8; ++j) h[j] = (_Float16)t[oc8*8+j][orow];
    *(f16x8*)(dst + (size_t)(tc*64+orow)*R + tr*64 + oc8*8) = h;
  }
}

// ---------------- 2) x fp32 -> fp16 ----------------
__global__ __launch_bounds__(256) void convert_x(const float* __restrict__ x,
                                                 _Float16* __restrict__ x16)
{
  size_t i = ((size_t)blockIdx.x*256 + threadIdx.x) * 4;
  f32x4 v = *(const f32x4*)(x + i);
  f16x4 h; h[0]=(_Float16)v[0]; h[1]=(_Float16)v[1]; h[2]=(_Float16)v[2]; h[3]=(_Float16)v[3];
  *(f16x4*)(x16 + i) = h;
}

// ---------------- 3) router logits, fp64 accumulation (tie-flip insurance) -----
__global__ __launch_bounds__(256) void router_kernel(const float* __restrict__ x,
    const float* __restrict__ rw, double* __restrict__ logits)
{
  int w = threadIdx.x >> 6, lane = threadIdx.x & 63;
  int tok = blockIdx.x*4 + w;
  const float* xr = x + (size_t)tok * HD;
  double acc[8] = {0,0,0,0,0,0,0,0};
  #pragma unroll
  for (int it = 0; it < 4; ++it) {
    int h = it*256 + lane*4;
    f32x4 xv = *(const f32x4*)(xr + h);
    #pragma unroll
    for (int j = 0; j < 4; ++j) {
      const float* wr = rw + (size_t)(h+j)*NE;
      f32x4 w0 = *(const f32x4*)wr;
      f32x4 w1v = *(const f32x4*)(wr+4);
      double xd = (double)xv[j];
      acc[0] += xd*(double)w0[0];  acc[1] += xd*(double)w0[1];
      acc[2] += xd*(double)w0[2];  acc[3] += xd*(double)w0[3];
      acc[4] += xd*(double)w1v[0]; acc[5] += xd*(double)w1v[1];
      acc[6] += xd*(double)w1v[2]; acc[7] += xd*(double)w1v[3];
    }
  }
  #pragma unroll
  for (int d = 1; d < 64; d <<= 1) {
    #pragma unroll
    for (int e = 0; e < 8; ++e) acc[e] += __shfl_xor(acc[e], d, 64);
  }
  if (lane == 0) {
    double* lp = logits + (size_t)tok*NE;
    #pragma unroll
    for (int e = 0; e < 8; ++e) lp[e] = acc[e];
  }
}

// ---------------- 4) top-2 gating, single block (token-order cumsums) ----------
__device__ __forceinline__ int wave_incl_scan(int v, int lane) {
  #pragma unroll
  for (int d = 1; d < 64; d <<= 1) {
    int u = __shfl_up(v, d, 64);
    if (lane >= d) v += u;
  }
  return v;
}

__global__ __launch_bounds__(256) void gating_kernel(const double* __restrict__ logits,
    int4* __restrict__ meta_i, f32x2* __restrict__ meta_f,
    int* __restrict__ slot_src, int* __restrict__ rows_dev)
{
  __shared__ unsigned char sE1[NTOK], sE2[NTOK];
  __shared__ float sG1[NTOK], sG2[NTOK];
  __shared__ int wsum1[8][4], wsum2[8][4];
  int tid = threadIdx.x, lane = tid & 63, w = tid >> 6;

  for (int i = tid; i < NSLOT; i += 256) slot_src[i] = 0;   // ws is poisoned; unused slots -> token 0

  int lc1[8] = {0,0,0,0,0,0,0,0}, lc2[8] = {0,0,0,0,0,0,0,0};
  #pragma unroll 1
  for (int i = 0; i < 16; ++i) {
    int n = tid*16 + i;
    const double* lp = logits + (size_t)n*NE;
    double l[8];
    #pragma unroll
    for (int e = 0; e < 8; ++e) l[e] = lp[e];
    int e1 = 0; double b1v = l[0];
    #pragma unroll
    for (int e = 1; e < 8; ++e) if (l[e] > b1v) { b1v = l[e]; e1 = e; }  // first-occurrence argmax
    double s = 0.0;
    #pragma unroll
    for (int e = 0; e < 8; ++e) s += exp(l[e] - b1v);
    int e2 = 0; double b2v = -1e300;
    #pragma unroll
    for (int e = 0; e < 8; ++e) if (e != e1 && l[e] > b2v) { b2v = l[e]; e2 = e; }
    sE1[n] = (unsigned char)e1; sE2[n] = (unsigned char)e2;
    sG1[n] = (float)(1.0 / s);
    sG2[n] = (float)(exp(b2v - b1v) / s);
    #pragma unroll
    for (int e = 0; e < 8; ++e) { lc1[e] += (e==e1); lc2[e] += (e==e2); }
  }
  int inc1[8], inc2[8];
  #pragma unroll
  for (int e = 0; e < 8; ++e) {
    inc1[e] = wave_incl_scan(lc1[e], lane);
    inc2[e] = wave_incl_scan(lc2[e], lane);
    if (lane == 63) { wsum1[e][w] = inc1[e]; wsum2[e][w] = inc2[e]; }
  }
  __syncthreads();
  int off1[8], off2[8], tot2[8], kept1[8];
  #pragma unroll
  for (int e = 0; e < 8; ++e) {
    int wp1=0, wp2=0, t1=0, t2=0;
    #pragma unroll
    for (int j = 0; j < 4; ++j) {
      int v1 = wsum1[e][j], v2 = wsum2[e][j];
      if (j < w) { wp1 += v1; wp2 += v2; }
      t1 += v1; t2 += v2;
    }
    off1[e] = inc1[e] - lc1[e] + wp1;
    off2[e] = inc2[e] - lc2[e] + wp2;
    tot2[e] = t2;
    kept1[e] = min(t1, CAP);          // = sum(mask1) after capacity drop
  }
  int r1[8], r2[8];
  #pragma unroll
  for (int e = 0; e < 8; ++e) { r1[e] = off1[e]; r2[e] = off2[e]; }
  #pragma unroll 1
  for (int i = 0; i < 16; ++i) {
    int n = tid*16 + i;
    int e1 = sE1[n], e2 = sE2[n];
    int p1 = 0, p2 = 0, k1off = 0;
    #pragma unroll
    for (int e = 0; e < 8; ++e) {
      if (e == e1) { p1 = r1[e]; r1[e] = p1 + 1; }
      if (e == e2) { p2 = r2[e]; r2[e] = p2 + 1; k1off = kept1[e]; }
    }
    int loc1 = (p1 < CAP) ? p1 : -1;
    int pp2 = p2 + k1off;
    int loc2 = (pp2 < CAP) ? pp2 : -1;
    float gg1 = (loc1 >= 0) ? sG1[n] : 0.0f;
    float gg2 = (loc2 >= 0) ? sG2[n] : 0.0f;
    float denom = fmaxf(gg1 + gg2, 1.1920929e-07f);  // finfo(f32).eps
    meta_i[n] = make_int4(e1, loc1, e2, loc2);
    f32x2 mf; mf[0] = gg1/denom; mf[1] = gg2/denom;
    meta_f[n] = mf;
    if (loc1 >= 0) slot_src[e1*CAP + loc1] = n;
    if (loc2 >= 0) slot_src[e2*CAP + loc2] = n;
  }
  if (tid < 8) {
    int rr = 0;
    #pragma unroll
    for (int e = 0; e < 8; ++e) if (e == tid) rr = min(kept1[e] + tot2[e], CAP);
    rows_dev[tid] = rr;     // occupied slots are contiguous [0, rows)
  }
}

// ---------------- 5/6) grouped GEMM, m97 structure + XOR-swizzled LDS ----------
// 128x128 tile, BK=64, 4 waves (2x2), 16x16x32 f16 MFMA, 4x4 acc tiles/wave.
// LDS swizzle: row r's K-chunk kc (16B granules) lives at slot kc^(r&7).
// global_load_lds forces LDS addr = base + lane*16, so the swizzle is applied by
// permuting WHICH chunk each lane fetches on the global side (free), and XORing
// the chunk index on the fragment-read side. Kills the 16-way bank-quad conflict
// (row stride = 128B = 32 banks) down to 2-way (free per m136).
template<int K, bool G1>
__global__ __launch_bounds__(256) void gemm_kernel(
    const _Float16* __restrict__ A0,     // x16 (G1) or mid16 (G2), row stride K
    const _Float16* __restrict__ Wexp,   // [E][NOUT][K] transposed weights
    const _Float16* __restrict__ Wshd,   // [NOUT][K]
    const float* __restrict__ BiasE,     // [E][NOUT]
    const float* __restrict__ BiasS,     // [NOUT]
    _Float16* __restrict__ Out,          // [TOTSLOT][NOUT]
    const int* __restrict__ slot_src,
    const int* __restrict__ rows_dev,
    int NOUT)
{
  int rt = blockIdx.y;
  int g, tile;
  if (rt < 80) { g = rt / 10; tile = rt % 10; } else { g = 8; tile = rt - 80; }
  int rows = (g < 8) ? rows_dev[g] : NTOK;
  if (tile * 128 >= rows) return;
  int slot_base = (g < 8) ? g * CAP : NSLOT;
  const _Float16* Bw = (g < 8) ? (Wexp + (size_t)g * NOUT * K) : Wshd;
  const float* bias = (g < 8) ? (BiasE + g * NOUT) : BiasS;
  int n0 = blockIdx.x * 128;

  __shared__ _Float16 Ash[128*64];   // [row][8 chunks of 8 halves], XOR-swizzled
  __shared__ _Float16 Bsh[128*64];

  int tid = threadIdx.x, lane = tid & 63, w = tid >> 6;
  int wm = w & 1, wn = w >> 1;

  // staging: lane (slot s = lane&7) of row-group fetches global chunk kc = s ^ (r&7)
  int kc = ((lane & 7) ^ ((lane >> 3) & 7)) * 8;   // halves offset within row
  const _Float16* aptr[4];
  const _Float16* bptr[4];
  #pragma unroll
  for (int i = 0; i < 4; ++i) {
    int r = (w*4 + i)*8 + (lane >> 3);
    int rg = tile*128 + r;
    size_t arow;
    if (G1) arow = (g < 8) ? (size_t)slot_src[g*CAP + rg] : (size_t)rg;
    else    arow = (size_t)(slot_base + rg);
    aptr[i] = A0 + arow * (size_t)K + kc;
    bptr[i] = Bw + (size_t)(n0 + r) * K + kc;
  }

  f32x4 acc[4][4];
  #pragma unroll
  for (int mi = 0; mi < 4; ++mi)
    #pragma unroll
    for (int ni = 0; ni < 4; ++ni)
      acc[mi][ni] = (f32x4)0.0f;

  for (int k0 = 0; k0 < K; k0 += 64) {
    #pragma unroll
    for (int i = 0; i < 4; ++i) load_lds16(aptr[i] + k0, &Ash[(w*4+i)*512]);
    #pragma unroll
    for (int i = 0; i < 4; ++i) load_lds16(bptr[i] + k0, &Bsh[(w*4+i)*512]);
    __syncthreads();
    #pragma unroll
    for (int ks = 0; ks < 2; ++ks) {
      // fragment chunk kc = ks*4 + (lane>>4); swizzled slot = kc ^ (row&7), row&7 = lane&7
      int sw = ((ks*4 + (lane>>4)) ^ (lane & 7)) * 8;
      f16x8 af[4], bf[4];
      #pragma unroll
      for (int mi = 0; mi < 4; ++mi)
        af[mi] = *(const f16x8*)&Ash[(wm*64 + mi*16 + (lane&15))*64 + sw];
      #pragma unroll
      for (int ni = 0; ni < 4; ++ni)
        bf[ni] = *(const f16x8*)&Bsh[(wn*64 + ni*16 + (lane&15))*64 + sw];
      #pragma unroll
      for (int mi = 0; mi < 4; ++mi)
        #pragma unroll
        for (int ni = 0; ni < 4; ++ni)
          acc[mi][ni] = __builtin_amdgcn_mfma_f32_16x16x32_f16(af[mi], bf[ni], acc[mi][ni], 0, 0, 0);
    }
    __syncthreads();
  }

  // epilogue: C/D layout col=lane&15, row=(lane>>4)*4+reg  (m89-corrected)
  #pragma unroll
  for (int mi = 0; mi < 4; ++mi) {
    #pragma unroll
    for (int r = 0; r < 4; ++r) {
      int m = wm*64 + mi*16 + (lane>>4)*4 + r;
      int rg = tile*128 + m;
      if (rg < rows) {
        size_t orow = (size_t)(slot_base + rg);
        #pragma unroll
        for (int ni = 0; ni < 4; ++ni) {
          int n = n0 + wn*64 + ni*16 + (lane & 15);
          float v = acc[mi][ni][r] + bias[n];
          if (G1) v = v / (1.0f + __expf(-v));   // SiLU
          Out[orow * (size_t)NOUT + n] = (_Float16)v;
        }
      }
    }
  }
}

// ---------------- 7) combine: y = g1*e1out + g2*e2out + 0.1*shared -------------
__global__ __launch_bounds__(256) void combine_kernel(const int4* __restrict__ meta_i,
    const f32x2* __restrict__ meta_f, const _Float16* __restrict__ out16,
    float* __restrict__ out)
{
  int n = blockIdx.x;
  int h = threadIdx.x * 4;
  int4 mi = meta_i[n];
  f32x2 mf = meta_f[n];
  f16x4 sv = *(const f16x4*)(out16 + (size_t)(NSLOT + n)*HD + h);
  f32x4 y;
  #pragma unroll
  for (int j = 0; j < 4; ++j) y[j] = 0.1f * (float)sv[j];
  if (mi.y >= 0) {
    f16x4 v = *(const f16x4*)(out16 + (size_t)(mi.x*CAP + mi.y)*HD + h);
    #pragma unroll
    for (int j = 0; j < 4; ++j) y[j] += mf[0] * (float)v[j];
  }
  if (mi.w >= 0) {
    f16x4 v = *(const f16x4*)(out16 + (size_t)(mi.z*CAP + mi.w)*HD + h);
    #pragma unroll
    for (int j = 0; j < 4; ++j) y[j] += mf[1] * (float)v[j];
  }
  *(f32x4*)(out + (size_t)n*HD + h) = y;
}

__global__ void fill_sentinel(float* out, int nelem) {
  int i = blockIdx.x*256 + threadIdx.x;
  if (i < nelem) out[i] = 12345.0f;   // distinctive: means ws_size was too small
}

// ---------------- host ----------------
extern "C" void kernel_launch(void* const* d_in, const int* in_sizes, int n_in,
                              void* d_out, int out_size, void* d_ws, size_t ws_size,
                              hipStream_t stream) {
  const float* x   = (const float*)d_in[0];
  const float* rw  = (const float*)d_in[1];
  const float* w1  = (const float*)d_in[2];
  const float* b1  = (const float*)d_in[3];
  const float* w2  = (const float*)d_in[4];
  const float* b2  = (const float*)d_in[5];
  const float* sw1 = (const float*)d_in[6];
  const float* sb1 = (const float*)d_in[7];
  const float* sw2 = (const float*)d_in[8];
  const float* sb2 = (const float*)d_in[9];
  float* out = (float*)d_out;

  char* p = (char*)d_ws;
  auto alloc = [&](size_t bytes) { char* r = p; p += (bytes + 255) & ~(size_t)255; return r; };
  _Float16* x16  = (_Float16*)alloc((size_t)NTOK*HD*2);
  _Float16* w1t  = (_Float16*)alloc((size_t)NE*FD*HD*2);
  _Float16* w2t  = (_Float16*)alloc((size_t)NE*HD*FD*2);
  _Float16* sw1t = (_Float16*)alloc((size_t)FD*HD*2);
  _Float16* sw2t = (_Float16*)alloc((size_t)HD*FD*2);
  _Float16* mid  = (_Float16*)alloc((size_t)TOTSLOT*FD*2);
  _Float16* o16  = (_Float16*)alloc((size_t)TOTSLOT*HD*2);
  double* logits = (double*)alloc((size_t)NTOK*NE*8);
  int4*   meta_i = (int4*)alloc((size_t)NTOK*16);
  f32x2*  meta_f = (f32x2*)alloc((size_t)NTOK*8);
  int* slot_src  = (int*)alloc((size_t)NSLOT*4);
  int* rows_dev  = (int*)alloc(64);
  size_t need = (size_t)(p - (char*)d_ws);
  if (need > ws_size) {
    fill_sentinel<<<(out_size+255)/256, 256, 0, stream>>>(out, out_size);
    return;
  }

  transpose_cvt<<<18*1024, 256, 0, stream>>>(w1, w2, sw1, sw2, w1t, w2t, sw1t, sw2t);
  convert_x<<<NTOK*HD/1024, 256, 0, stream>>>(x, x16);
  router_kernel<<<NTOK/4, 256, 0, stream>>>(x, rw, logits);
  gating_kernel<<<1, 256, 0, stream>>>(logits, meta_i, meta_f, slot_src, rows_dev);
  gemm_kernel<HD, true><<<dim3(FD/128, 112), 256, 0, stream>>>(
      x16, w1t, sw1t, b1, sb1, mid, slot_src, rows_dev, FD);
  gemm_kernel<FD, false><<<dim3(HD/128, 112), 256, 0, stream>>>(
      mid, w2t, sw2t, b2, sb2, o16, slot_src, rows_dev, HD);
  combine_kernel<<<NTOK, 256, 0, stream>>>(meta_i, meta_f, o16, out);
}

// Round 3
// 718.450 us; speedup vs baseline: 1.1313x; 1.0613x over previous
//
#include <hip/hip_runtime.h>
#include <cstdint>
#include <cstddef>

// ---------------- problem constants ----------------
#define HD    1024
#define FD    4096
#define NE    8
#define NTOK  4096            // 2*2048
#define CAP   1280            // ceil(2*1.25*4096/8)
#define NSLOT (NE*CAP)        // 10240 expert slots
#define TOTSLOT (NSLOT+NTOK)  // + shared rows

typedef float    f32x4 __attribute__((ext_vector_type(4)));
typedef float    f32x2 __attribute__((ext_vector_type(2)));
typedef _Float16 f16x8 __attribute__((ext_vector_type(8)));
typedef _Float16 f16x4 __attribute__((ext_vector_type(4)));

typedef __attribute__((address_space(3))) unsigned int as3_u32;
typedef __attribute__((address_space(1))) unsigned int as1_u32;

__device__ __forceinline__ void load_lds16(const _Float16* g, _Float16* l) {
  __builtin_amdgcn_global_load_lds((const as1_u32*)g, (as3_u32*)l, 16, 0, 0);
}

// ---------------- 1) weight convert+transpose v2 + x convert -------------------
// 64(src rows) x 256(src cols) tiles: 1KB contiguous read per row visit (was 256B),
// fp16 in LDS (33KB), f16x8 writes. Blocks 0..4607 = transpose, 4608..4863 = x cvt.
__global__ __launch_bounds__(512) void transpose_cvt(
    const float* __restrict__ w1, const float* __restrict__ w2,
    const float* __restrict__ sw1, const float* __restrict__ sw2,
    const float* __restrict__ x,
    _Float16* __restrict__ w1t, _Float16* __restrict__ w2t,
    _Float16* __restrict__ sw1t, _Float16* __restrict__ sw2t,
    _Float16* __restrict__ x16)
{
  int b = blockIdx.x;
  int tid = threadIdx.x;
  if (b >= 4608) {                       // x: 4096*1024 f32 -> f16, 256 blocks
    int cb = b - 4608;
    #pragma unroll
    for (int it = 0; it < 8; ++it) {
      size_t i = (size_t)cb*16384 + (size_t)(it*512 + tid)*4;
      f32x4 v = *(const f32x4*)(x + i);
      f16x4 h; h[0]=(_Float16)v[0]; h[1]=(_Float16)v[1]; h[2]=(_Float16)v[2]; h[3]=(_Float16)v[3];
      *(f16x4*)(x16 + i) = h;
    }
    return;
  }
  const float* src; _Float16* dst; int R, C;
  if (b < 2048)      { int e = b>>8;        src = w1 + (size_t)e*HD*FD; dst = w1t + (size_t)e*FD*HD; R=HD; C=FD; }
  else if (b < 4096) { int e = (b-2048)>>8; src = w2 + (size_t)e*FD*HD; dst = w2t + (size_t)e*HD*FD; R=FD; C=HD; }
  else if (b < 4352) { src = sw1; dst = sw1t; R=HD; C=FD; }
  else               { src = sw2; dst = sw2t; R=FD; C=HD; }
  int tile = b & 255;
  int ctiles = C >> 8;                   // 16 (C=4096) or 4 (C=1024)
  int tr = tile / ctiles, tc = tile - tr*ctiles;
  int r0 = tr*64, c0 = tc*256;

  __shared__ _Float16 t[64][264];        // +8 halves pad: keeps 16B align, breaks conflicts
  #pragma unroll
  for (int it = 0; it < 8; ++it) {
    int idx = it*512 + tid;              // 4096 f32x4 chunks
    int row = idx >> 6, c4 = idx & 63;
    f32x4 v = *(const f32x4*)(src + (size_t)(r0+row)*C + c0 + c4*4);
    f16x4 h; h[0]=(_Float16)v[0]; h[1]=(_Float16)v[1]; h[2]=(_Float16)v[2]; h[3]=(_Float16)v[3];
    *(f16x4*)&t[row][c4*4] = h;
  }
  __syncthreads();
  #pragma unroll
  for (int it = 0; it < 4; ++it) {
    int idx = it*512 + tid;              // 2048 f16x8 chunks
    int d = idx >> 3, c8 = idx & 7;      // d = dst row (src col), c8*8 = dst col chunk
    f16x8 h;
    #pragma unroll
    for (int j = 0; j < 8; ++j) h[j] = t[c8*8+j][d];
    *(f16x8*)(dst + (size_t)(c0+d)*R + r0 + c8*8) = h;
  }
}

// ---------------- 3) router logits, fp64 accumulation (tie-flip insurance) -----
__global__ __launch_bounds__(256) void router_kernel(const float* __restrict__ x,
    const float* __restrict__ rw, double* __restrict__ logits)
{
  int w = threadIdx.x >> 6, lane = threadIdx.x & 63;
  int tok = blockIdx.x*4 + w;
  const float* xr = x + (size_t)tok * HD;
  double acc[8] = {0,0,0,0,0,0,0,0};
  #pragma unroll
  for (int it = 0; it < 4; ++it) {
    int h = it*256 + lane*4;
    f32x4 xv = *(const f32x4*)(xr + h);
    #pragma unroll
    for (int j = 0; j < 4; ++j) {
      const float* wr = rw + (size_t)(h+j)*NE;
      f32x4 w0 = *(const f32x4*)wr;
      f32x4 w1v = *(const f32x4*)(wr+4);
      double xd = (double)xv[j];
      acc[0] += xd*(double)w0[0];  acc[1] += xd*(double)w0[1];
      acc[2] += xd*(double)w0[2];  acc[3] += xd*(double)w0[3];
      acc[4] += xd*(double)w1v[0]; acc[5] += xd*(double)w1v[1];
      acc[6] += xd*(double)w1v[2]; acc[7] += xd*(double)w1v[3];
    }
  }
  #pragma unroll
  for (int d = 1; d < 64; d <<= 1) {
    #pragma unroll
    for (int e = 0; e < 8; ++e) acc[e] += __shfl_xor(acc[e], d, 64);
  }
  if (lane == 0) {
    double* lp = logits + (size_t)tok*NE;
    #pragma unroll
    for (int e = 0; e < 8; ++e) lp[e] = acc[e];
  }
}

// ---------------- 4) top-2 gating v2: 1024 threads, float expf -----------------
__device__ __forceinline__ int wave_incl_scan(int v, int lane) {
  #pragma unroll
  for (int d = 1; d < 64; d <<= 1) {
    int u = __shfl_up(v, d, 64);
    if (lane >= d) v += u;
  }
  return v;
}

__global__ __launch_bounds__(1024) void gating_kernel(const double* __restrict__ logits,
    int4* __restrict__ meta_i, f32x2* __restrict__ meta_f,
    int* __restrict__ slot_src, int* __restrict__ rows_dev)
{
  __shared__ unsigned char sE1[NTOK], sE2[NTOK];
  __shared__ float sG1[NTOK], sG2[NTOK];
  __shared__ int wsum1[8][16], wsum2[8][16];
  int tid = threadIdx.x, lane = tid & 63, w = tid >> 6;

  for (int i = tid; i < NSLOT; i += 1024) slot_src[i] = 0;  // unused slots -> token 0

  int lc1[8] = {0,0,0,0,0,0,0,0}, lc2[8] = {0,0,0,0,0,0,0,0};
  #pragma unroll 1
  for (int i = 0; i < 4; ++i) {
    int n = tid*4 + i;
    const double* lp = logits + (size_t)n*NE;
    double l[8];
    #pragma unroll
    for (int e = 0; e < 8; ++e) l[e] = lp[e];
    int e1 = 0; double b1v = l[0];
    #pragma unroll
    for (int e = 1; e < 8; ++e) if (l[e] > b1v) { b1v = l[e]; e1 = e; }  // first-occurrence argmax
    float s = 0.0f;
    #pragma unroll
    for (int e = 0; e < 8; ++e) s += __expf((float)(l[e] - b1v));
    int e2 = 0; double b2v = -1e300;
    #pragma unroll
    for (int e = 0; e < 8; ++e) if (e != e1 && l[e] > b2v) { b2v = l[e]; e2 = e; }
    sE1[n] = (unsigned char)e1; sE2[n] = (unsigned char)e2;
    sG1[n] = 1.0f / s;
    sG2[n] = __expf((float)(b2v - b1v)) / s;
    #pragma unroll
    for (int e = 0; e < 8; ++e) { lc1[e] += (e==e1); lc2[e] += (e==e2); }
  }
  int inc1[8], inc2[8];
  #pragma unroll
  for (int e = 0; e < 8; ++e) {
    inc1[e] = wave_incl_scan(lc1[e], lane);
    inc2[e] = wave_incl_scan(lc2[e], lane);
    if (lane == 63) { wsum1[e][w] = inc1[e]; wsum2[e][w] = inc2[e]; }
  }
  __syncthreads();
  int off1[8], off2[8], tot2[8], kept1[8];
  #pragma unroll
  for (int e = 0; e < 8; ++e) {
    int wp1=0, wp2=0, t1=0, t2=0;
    #pragma unroll
    for (int j = 0; j < 16; ++j) {
      int v1 = wsum1[e][j], v2 = wsum2[e][j];
      if (j < w) { wp1 += v1; wp2 += v2; }
      t1 += v1; t2 += v2;
    }
    off1[e] = inc1[e] - lc1[e] + wp1;
    off2[e] = inc2[e] - lc2[e] + wp2;
    tot2[e] = t2;
    kept1[e] = min(t1, CAP);          // = sum(mask1) after capacity drop
  }
  int r1[8], r2[8];
  #pragma unroll
  for (int e = 0; e < 8; ++e) { r1[e] = off1[e]; r2[e] = off2[e]; }
  #pragma unroll 1
  for (int i = 0; i < 4; ++i) {
    int n = tid*4 + i;
    int e1 = sE1[n], e2 = sE2[n];
    int p1 = 0, p2 = 0, k1off = 0;
    #pragma unroll
    for (int e = 0; e < 8; ++e) {
      if (e == e1) { p1 = r1[e]; r1[e] = p1 + 1; }
      if (e == e2) { p2 = r2[e]; r2[e] = p2 + 1; k1off = kept1[e]; }
    }
    int loc1 = (p1 < CAP) ? p1 : -1;
    int pp2 = p2 + k1off;
    int loc2 = (pp2 < CAP) ? pp2 : -1;
    float gg1 = (loc1 >= 0) ? sG1[n] : 0.0f;
    float gg2 = (loc2 >= 0) ? sG2[n] : 0.0f;
    float denom = fmaxf(gg1 + gg2, 1.1920929e-07f);  // finfo(f32).eps
    meta_i[n] = make_int4(e1, loc1, e2, loc2);
    f32x2 mf; mf[0] = gg1/denom; mf[1] = gg2/denom;
    meta_f[n] = mf;
    if (loc1 >= 0) slot_src[e1*CAP + loc1] = n;
    if (loc2 >= 0) slot_src[e2*CAP + loc2] = n;
  }
  if (tid < 8) {
    int rr = 0;
    #pragma unroll
    for (int e = 0; e < 8; ++e) if (e == tid) rr = min(kept1[e] + tot2[e], CAP);
    rows_dev[tid] = rr;     // occupied slots are contiguous [0, rows)
  }
}

// ---------------- 5/6) grouped GEMM: swizzled LDS + XCD-co-located n-tiles -----
// 128x128 tile, BK=64, 4 waves (2x2), 16x16x32 f16 MFMA, 4x4 acc/wave.
// 1-D grid; decode puts all NXT n-tile blocks of one row-tile on the SAME
// blockIdx%8 residue (-> same XCD under round-robin dispatch) so the shared
// A row-tile is fetched once into that XCD's L2 instead of 8x from HBM/L3.
template<int K, int NOUT, bool G1>
__global__ __launch_bounds__(256) void gemm_kernel(
    const _Float16* __restrict__ A0,     // x16 (G1) or mid16 (G2), row stride K
    const _Float16* __restrict__ Wexp,   // [E][NOUT][K] transposed weights
    const _Float16* __restrict__ Wshd,   // [NOUT][K]
    const float* __restrict__ BiasE,     // [E][NOUT]
    const float* __restrict__ BiasS,     // [NOUT]
    _Float16* __restrict__ Out,          // [TOTSLOT][NOUT]
    const int* __restrict__ slot_src,
    const int* __restrict__ rows_dev)
{
  constexpr int NXT = NOUT / 128;        // n-tiles: 32 (gemm1) / 8 (gemm2)
  int bid = blockIdx.x;                  // grid = 112*NXT = 8 XCDs * 14*NXT
  int idx = (bid & 7) * (14 * NXT) + (bid >> 3);
  int rt = idx / NXT;                    // row-tile 0..111; XCD c owns rt in [c*14,(c+1)*14)
  int n0 = (idx - rt * NXT) * 128;

  int g, tile;
  if (rt < 80) { g = rt / 10; tile = rt % 10; } else { g = 8; tile = rt - 80; }
  int rows = (g < 8) ? rows_dev[g] : NTOK;
  if (tile * 128 >= rows) return;
  int slot_base = (g < 8) ? g * CAP : NSLOT;
  const _Float16* Bw = (g < 8) ? (Wexp + (size_t)g * NOUT * K) : Wshd;
  const float* bias = (g < 8) ? (BiasE + g * NOUT) : BiasS;

  __shared__ _Float16 Ash[128*64];   // [row][8 chunks of 8 halves], XOR-swizzled
  __shared__ _Float16 Bsh[128*64];

  int tid = threadIdx.x, lane = tid & 63, w = tid >> 6;
  int wm = w & 1, wn = w >> 1;

  // staging: slot s = lane&7 of row-group fetches global chunk kc = s ^ (r&7)
  int kc = ((lane & 7) ^ ((lane >> 3) & 7)) * 8;
  const _Float16* aptr[4];
  const _Float16* bptr[4];
  #pragma unroll
  for (int i = 0; i < 4; ++i) {
    int r = (w*4 + i)*8 + (lane >> 3);
    int rg = tile*128 + r;
    size_t arow;
    if (G1) arow = (g < 8) ? (size_t)slot_src[g*CAP + rg] : (size_t)rg;
    else    arow = (size_t)(slot_base + rg);
    aptr[i] = A0 + arow * (size_t)K + kc;
    bptr[i] = Bw + (size_t)(n0 + r) * K + kc;
  }

  f32x4 acc[4][4];
  #pragma unroll
  for (int mi = 0; mi < 4; ++mi)
    #pragma unroll
    for (int ni = 0; ni < 4; ++ni)
      acc[mi][ni] = (f32x4)0.0f;

  for (int k0 = 0; k0 < K; k0 += 64) {
    #pragma unroll
    for (int i = 0; i < 4; ++i) load_lds16(aptr[i] + k0, &Ash[(w*4+i)*512]);
    #pragma unroll
    for (int i = 0; i < 4; ++i) load_lds16(bptr[i] + k0, &Bsh[(w*4+i)*512]);
    __syncthreads();
    #pragma unroll
    for (int ks = 0; ks < 2; ++ks) {
      int sw = ((ks*4 + (lane>>4)) ^ (lane & 7)) * 8;   // chunk ^ (row&7)
      f16x8 af[4], bf[4];
      #pragma unroll
      for (int mi = 0; mi < 4; ++mi)
        af[mi] = *(const f16x8*)&Ash[(wm*64 + mi*16 + (lane&15))*64 + sw];
      #pragma unroll
      for (int ni = 0; ni < 4; ++ni)
        bf[ni] = *(const f16x8*)&Bsh[(wn*64 + ni*16 + (lane&15))*64 + sw];
      #pragma unroll
      for (int mi = 0; mi < 4; ++mi)
        #pragma unroll
        for (int ni = 0; ni < 4; ++ni)
          acc[mi][ni] = __builtin_amdgcn_mfma_f32_16x16x32_f16(af[mi], bf[ni], acc[mi][ni], 0, 0, 0);
    }
    __syncthreads();
  }

  // epilogue: C/D layout col=lane&15, row=(lane>>4)*4+reg  (m89-corrected)
  #pragma unroll
  for (int mi = 0; mi < 4; ++mi) {
    #pragma unroll
    for (int r = 0; r < 4; ++r) {
      int m = wm*64 + mi*16 + (lane>>4)*4 + r;
      int rg = tile*128 + m;
      if (rg < rows) {
        size_t orow = (size_t)(slot_base + rg);
        #pragma unroll
        for (int ni = 0; ni < 4; ++ni) {
          int n = n0 + wn*64 + ni*16 + (lane & 15);
          float v = acc[mi][ni][r] + bias[n];
          if (G1) v = v / (1.0f + __expf(-v));   // SiLU
          Out[orow * (size_t)NOUT + n] = (_Float16)v;
        }
      }
    }
  }
}

// ---------------- 7) combine: y = g1*e1out + g2*e2out + 0.1*shared -------------
__global__ __launch_bounds__(256) void combine_kernel(const int4* __restrict__ meta_i,
    const f32x2* __restrict__ meta_f, const _Float16* __restrict__ out16,
    float* __restrict__ out)
{
  int n = blockIdx.x;
  int h = threadIdx.x * 4;
  int4 mi = meta_i[n];
  f32x2 mf = meta_f[n];
  f16x4 sv = *(const f16x4*)(out16 + (size_t)(NSLOT + n)*HD + h);
  f32x4 y;
  #pragma unroll
  for (int j = 0; j < 4; ++j) y[j] = 0.1f * (float)sv[j];
  if (mi.y >= 0) {
    f16x4 v = *(const f16x4*)(out16 + (size_t)(mi.x*CAP + mi.y)*HD + h);
    #pragma unroll
    for (int j = 0; j < 4; ++j) y[j] += mf[0] * (float)v[j];
  }
  if (mi.w >= 0) {
    f16x4 v = *(const f16x4*)(out16 + (size_t)(mi.z*CAP + mi.w)*HD + h);
    #pragma unroll
    for (int j = 0; j < 4; ++j) y[j] += mf[1] * (float)v[j];
  }
  *(f32x4*)(out + (size_t)n*HD + h) = y;
}

__global__ void fill_sentinel(float* out, int nelem) {
  int i = blockIdx.x*256 + threadIdx.x;
  if (i < nelem) out[i] = 12345.0f;   // distinctive: means ws_size was too small
}

// ---------------- host ----------------
extern "C" void kernel_launch(void* const* d_in, const int* in_sizes, int n_in,
                              void* d_out, int out_size, void* d_ws, size_t ws_size,
                              hipStream_t stream) {
  const float* x   = (const float*)d_in[0];
  const float* rw  = (const float*)d_in[1];
  const float* w1  = (const float*)d_in[2];
  const float* b1  = (const float*)d_in[3];
  const float* w2  = (const float*)d_in[4];
  const float* b2  = (const float*)d_in[5];
  const float* sw1 = (const float*)d_in[6];
  const float* sb1 = (const float*)d_in[7];
  const float* sw2 = (const float*)d_in[8];
  const float* sb2 = (const float*)d_in[9];
  float* out = (float*)d_out;

  char* p = (char*)d_ws;
  auto alloc = [&](size_t bytes) { char* r = p; p += (bytes + 255) & ~(size_t)255; return r; };
  _Float16* x16  = (_Float16*)alloc((size_t)NTOK*HD*2);
  _Float16* w1t  = (_Float16*)alloc((size_t)NE*FD*HD*2);
  _Float16* w2t  = (_Float16*)alloc((size_t)NE*HD*FD*2);
  _Float16* sw1t = (_Float16*)alloc((size_t)FD*HD*2);
  _Float16* sw2t = (_Float16*)alloc((size_t)HD*FD*2);
  _Float16* mid  = (_Float16*)alloc((size_t)TOTSLOT*FD*2);
  _Float16* o16  = (_Float16*)alloc((size_t)TOTSLOT*HD*2);
  double* logits = (double*)alloc((size_t)NTOK*NE*8);
  int4*   meta_i = (int4*)alloc((size_t)NTOK*16);
  f32x2*  meta_f = (f32x2*)alloc((size_t)NTOK*8);
  int* slot_src  = (int*)alloc((size_t)NSLOT*4);
  int* rows_dev  = (int*)alloc(64);
  size_t need = (size_t)(p - (char*)d_ws);
  if (need > ws_size) {
    fill_sentinel<<<(out_size+255)/256, 256, 0, stream>>>(out, out_size);
    return;
  }

  transpose_cvt<<<4864, 512, 0, stream>>>(w1, w2, sw1, sw2, x, w1t, w2t, sw1t, sw2t, x16);
  router_kernel<<<NTOK/4, 256, 0, stream>>>(x, rw, logits);
  gating_kernel<<<1, 1024, 0, stream>>>(logits, meta_i, meta_f, slot_src, rows_dev);
  gemm_kernel<HD, FD, true><<<112*(FD/128), 256, 0, stream>>>(
      x16, w1t, sw1t, b1, sb1, mid, slot_src, rows_dev);
  gemm_kernel<FD, HD, false><<<112*(HD/128), 256, 0, stream>>>(
      mid, w2t, sw2t, b2, sb2, o16, slot_src, rows_dev);
  combine_kernel<<<NTOK, 256, 0, stream>>>(meta_i, meta_f, o16, out);
}

// Round 4
// 713.403 us; speedup vs baseline: 1.1393x; 1.0071x over previous
//
#include <hip/hip_runtime.h>
#include <cstdint>
#include <cstddef>

// ---------------- problem constants ----------------
#define HD    1024
#define FD    4096
#define NE    8
#define NTOK  4096            // 2*2048
#define CAP   1280            // ceil(2*1.25*4096/8)
#define NSLOT (NE*CAP)        // 10240 expert slots
#define TOTSLOT (NSLOT+NTOK)  // + shared rows

typedef float    f32x4  __attribute__((ext_vector_type(4)));
typedef float    f32x2  __attribute__((ext_vector_type(2)));
typedef float    f32x16 __attribute__((ext_vector_type(16)));
typedef _Float16 f16x8  __attribute__((ext_vector_type(8)));
typedef _Float16 f16x4  __attribute__((ext_vector_type(4)));

typedef __attribute__((address_space(3))) unsigned int as3_u32;
typedef __attribute__((address_space(1))) unsigned int as1_u32;

__device__ __forceinline__ void load_lds16(const _Float16* g, _Float16* l) {
  __builtin_amdgcn_global_load_lds((const as1_u32*)g, (as3_u32*)l, 16, 0, 0);
}

// ---------------- 1) weight convert+transpose + x convert ----------------------
// 64(src rows) x 256(src cols) tiles: 1KB contiguous read per row visit,
// fp16 in LDS (33KB), f16x8 writes. Blocks 0..4607 = transpose, 4608..4863 = x cvt.
__global__ __launch_bounds__(512) void transpose_cvt(
    const float* __restrict__ w1, const float* __restrict__ w2,
    const float* __restrict__ sw1, const float* __restrict__ sw2,
    const float* __restrict__ x,
    _Float16* __restrict__ w1t, _Float16* __restrict__ w2t,
    _Float16* __restrict__ sw1t, _Float16* __restrict__ sw2t,
    _Float16* __restrict__ x16)
{
  int b = blockIdx.x;
  int tid = threadIdx.x;
  if (b >= 4608) {                       // x: 4096*1024 f32 -> f16, 256 blocks
    int cb = b - 4608;
    #pragma unroll
    for (int it = 0; it < 8; ++it) {
      size_t i = (size_t)cb*16384 + (size_t)(it*512 + tid)*4;
      f32x4 v = *(const f32x4*)(x + i);
      f16x4 h; h[0]=(_Float16)v[0]; h[1]=(_Float16)v[1]; h[2]=(_Float16)v[2]; h[3]=(_Float16)v[3];
      *(f16x4*)(x16 + i) = h;
    }
    return;
  }
  const float* src; _Float16* dst; int R, C;
  if (b < 2048)      { int e = b>>8;        src = w1 + (size_t)e*HD*FD; dst = w1t + (size_t)e*FD*HD; R=HD; C=FD; }
  else if (b < 4096) { int e = (b-2048)>>8; src = w2 + (size_t)e*FD*HD; dst = w2t + (size_t)e*HD*FD; R=FD; C=HD; }
  else if (b < 4352) { src = sw1; dst = sw1t; R=HD; C=FD; }
  else               { src = sw2; dst = sw2t; R=FD; C=HD; }
  int tile = b & 255;
  int ctiles = C >> 8;                   // 16 (C=4096) or 4 (C=1024)
  int tr = tile / ctiles, tc = tile - tr*ctiles;
  int r0 = tr*64, c0 = tc*256;

  __shared__ _Float16 t[64][264];        // +8 halves pad: keeps 16B align, breaks conflicts
  #pragma unroll
  for (int it = 0; it < 8; ++it) {
    int idx = it*512 + tid;              // 4096 f32x4 chunks
    int row = idx >> 6, c4 = idx & 63;
    f32x4 v = *(const f32x4*)(src + (size_t)(r0+row)*C + c0 + c4*4);
    f16x4 h; h[0]=(_Float16)v[0]; h[1]=(_Float16)v[1]; h[2]=(_Float16)v[2]; h[3]=(_Float16)v[3];
    *(f16x4*)&t[row][c4*4] = h;
  }
  __syncthreads();
  #pragma unroll
  for (int it = 0; it < 4; ++it) {
    int idx = it*512 + tid;              // 2048 f16x8 chunks
    int d = idx >> 3, c8 = idx & 7;      // d = dst row (src col), c8*8 = dst col chunk
    f16x8 h;
    #pragma unroll
    for (int j = 0; j < 8; ++j) h[j] = t[c8*8+j][d];
    *(f16x8*)(dst + (size_t)(c0+d)*R + r0 + c8*8) = h;
  }
}

// ---------------- 3) router logits, fp64 accumulation (tie-flip insurance) -----
__global__ __launch_bounds__(256) void router_kernel(const float* __restrict__ x,
    const float* __restrict__ rw, double* __restrict__ logits)
{
  int w = threadIdx.x >> 6, lane = threadIdx.x & 63;
  int tok = blockIdx.x*4 + w;
  const float* xr = x + (size_t)tok * HD;
  double acc[8] = {0,0,0,0,0,0,0,0};
  #pragma unroll
  for (int it = 0; it < 4; ++it) {
    int h = it*256 + lane*4;
    f32x4 xv = *(const f32x4*)(xr + h);
    #pragma unroll
    for (int j = 0; j < 4; ++j) {
      const float* wr = rw + (size_t)(h+j)*NE;
      f32x4 w0 = *(const f32x4*)wr;
      f32x4 w1v = *(const f32x4*)(wr+4);
      double xd = (double)xv[j];
      acc[0] += xd*(double)w0[0];  acc[1] += xd*(double)w0[1];
      acc[2] += xd*(double)w0[2];  acc[3] += xd*(double)w0[3];
      acc[4] += xd*(double)w1v[0]; acc[5] += xd*(double)w1v[1];
      acc[6] += xd*(double)w1v[2]; acc[7] += xd*(double)w1v[3];
    }
  }
  #pragma unroll
  for (int d = 1; d < 64; d <<= 1) {
    #pragma unroll
    for (int e = 0; e < 8; ++e) acc[e] += __shfl_xor(acc[e], d, 64);
  }
  if (lane == 0) {
    double* lp = logits + (size_t)tok*NE;
    #pragma unroll
    for (int e = 0; e < 8; ++e) lp[e] = acc[e];
  }
}

// ---------------- 4) top-2 gating: 1024 threads, float expf --------------------
__device__ __forceinline__ int wave_incl_scan(int v, int lane) {
  #pragma unroll
  for (int d = 1; d < 64; d <<= 1) {
    int u = __shfl_up(v, d, 64);
    if (lane >= d) v += u;
  }
  return v;
}

__global__ __launch_bounds__(1024) void gating_kernel(const double* __restrict__ logits,
    int4* __restrict__ meta_i, f32x2* __restrict__ meta_f,
    int* __restrict__ slot_src, int* __restrict__ rows_dev)
{
  __shared__ unsigned char sE1[NTOK], sE2[NTOK];
  __shared__ float sG1[NTOK], sG2[NTOK];
  __shared__ int wsum1[8][16], wsum2[8][16];
  int tid = threadIdx.x, lane = tid & 63, w = tid >> 6;

  for (int i = tid; i < NSLOT; i += 1024) slot_src[i] = 0;  // unused slots -> token 0

  int lc1[8] = {0,0,0,0,0,0,0,0}, lc2[8] = {0,0,0,0,0,0,0,0};
  #pragma unroll 1
  for (int i = 0; i < 4; ++i) {
    int n = tid*4 + i;
    const double* lp = logits + (size_t)n*NE;
    double l[8];
    #pragma unroll
    for (int e = 0; e < 8; ++e) l[e] = lp[e];
    int e1 = 0; double b1v = l[0];
    #pragma unroll
    for (int e = 1; e < 8; ++e) if (l[e] > b1v) { b1v = l[e]; e1 = e; }  // first-occurrence argmax
    float s = 0.0f;
    #pragma unroll
    for (int e = 0; e < 8; ++e) s += __expf((float)(l[e] - b1v));
    int e2 = 0; double b2v = -1e300;
    #pragma unroll
    for (int e = 0; e < 8; ++e) if (e != e1 && l[e] > b2v) { b2v = l[e]; e2 = e; }
    sE1[n] = (unsigned char)e1; sE2[n] = (unsigned char)e2;
    sG1[n] = 1.0f / s;
    sG2[n] = __expf((float)(b2v - b1v)) / s;
    #pragma unroll
    for (int e = 0; e < 8; ++e) { lc1[e] += (e==e1); lc2[e] += (e==e2); }
  }
  int inc1[8], inc2[8];
  #pragma unroll
  for (int e = 0; e < 8; ++e) {
    inc1[e] = wave_incl_scan(lc1[e], lane);
    inc2[e] = wave_incl_scan(lc2[e], lane);
    if (lane == 63) { wsum1[e][w] = inc1[e]; wsum2[e][w] = inc2[e]; }
  }
  __syncthreads();
  int off1[8], off2[8], tot2[8], kept1[8];
  #pragma unroll
  for (int e = 0; e < 8; ++e) {
    int wp1=0, wp2=0, t1=0, t2=0;
    #pragma unroll
    for (int j = 0; j < 16; ++j) {
      int v1 = wsum1[e][j], v2 = wsum2[e][j];
      if (j < w) { wp1 += v1; wp2 += v2; }
      t1 += v1; t2 += v2;
    }
    off1[e] = inc1[e] - lc1[e] + wp1;
    off2[e] = inc2[e] - lc2[e] + wp2;
    tot2[e] = t2;
    kept1[e] = min(t1, CAP);          // = sum(mask1) after capacity drop
  }
  int r1[8], r2[8];
  #pragma unroll
  for (int e = 0; e < 8; ++e) { r1[e] = off1[e]; r2[e] = off2[e]; }
  #pragma unroll 1
  for (int i = 0; i < 4; ++i) {
    int n = tid*4 + i;
    int e1 = sE1[n], e2 = sE2[n];
    int p1 = 0, p2 = 0, k1off = 0;
    #pragma unroll
    for (int e = 0; e < 8; ++e) {
      if (e == e1) { p1 = r1[e]; r1[e] = p1 + 1; }
      if (e == e2) { p2 = r2[e]; r2[e] = p2 + 1; k1off = kept1[e]; }
    }
    int loc1 = (p1 < CAP) ? p1 : -1;
    int pp2 = p2 + k1off;
    int loc2 = (pp2 < CAP) ? pp2 : -1;
    float gg1 = (loc1 >= 0) ? sG1[n] : 0.0f;
    float gg2 = (loc2 >= 0) ? sG2[n] : 0.0f;
    float denom = fmaxf(gg1 + gg2, 1.1920929e-07f);  // finfo(f32).eps
    meta_i[n] = make_int4(e1, loc1, e2, loc2);
    f32x2 mf; mf[0] = gg1/denom; mf[1] = gg2/denom;
    meta_f[n] = mf;
    if (loc1 >= 0) slot_src[e1*CAP + loc1] = n;
    if (loc2 >= 0) slot_src[e2*CAP + loc2] = n;
  }
  if (tid < 8) {
    int rr = 0;
    #pragma unroll
    for (int e = 0; e < 8; ++e) if (e == tid) rr = min(kept1[e] + tot2[e], CAP);
    rows_dev[tid] = rr;     // occupied slots are contiguous [0, rows)
  }
}

// ---------------- 5/6) grouped GEMM: 32x32x16 MFMA + per-GEMM XCD mapping ------
// 128x128 tile, BK=64, 4 waves (2x2), each wave 2x2 tiles of 32x32x16 f16 MFMA.
// Mapping: gemm1 (A small 8MB, B big 72MB): n-tile fastest -> each XCD owns a
//   4-n-tile B slab (1MB/expert, L2-resident across the expert's row-tiles);
//   A re-read x8 absorbed by L3 (142MB fetch measured in r2).
// gemm2 (A big 117MB, B 72MB): co-locate all 8 n-tiles of a row-tile on one XCD
//   so A is fetched once (447->~230MB measured r2->r3).
template<int K, int NOUT, bool G1>
__global__ __launch_bounds__(256) void gemm_kernel(
    const _Float16* __restrict__ A0,     // x16 (G1) or mid16 (G2), row stride K
    const _Float16* __restrict__ Wexp,   // [E][NOUT][K] transposed weights
    const _Float16* __restrict__ Wshd,   // [NOUT][K]
    const float* __restrict__ BiasE,     // [E][NOUT]
    const float* __restrict__ BiasS,     // [NOUT]
    _Float16* __restrict__ Out,          // [TOTSLOT][NOUT]
    const int* __restrict__ slot_src,
    const int* __restrict__ rows_dev)
{
  constexpr int NXT = NOUT / 128;        // n-tiles: 32 (gemm1) / 8 (gemm2)
  int bid = blockIdx.x;
  int rt, nt;
  if (G1) {                              // n-fastest, natural round-robin
    nt = bid & (NXT - 1); rt = bid >> 5; // NXT==32
  } else {                               // co-located row-tiles per XCD
    int idx = (bid & 7) * (14 * NXT) + (bid >> 3);
    rt = idx / NXT; nt = idx - rt * NXT;
  }
  int n0 = nt * 128;

  int g, tile;
  if (rt < 80) { g = rt / 10; tile = rt % 10; } else { g = 8; tile = rt - 80; }
  int rows = (g < 8) ? rows_dev[g] : NTOK;
  if (tile * 128 >= rows) return;
  int slot_base = (g < 8) ? g * CAP : NSLOT;
  const _Float16* Bw = (g < 8) ? (Wexp + (size_t)g * NOUT * K) : Wshd;
  const float* bias = (g < 8) ? (BiasE + g * NOUT) : BiasS;

  __shared__ _Float16 Ash[128*64];   // [row][8 chunks of 8 halves], chunk c at slot c^(row&7)
  __shared__ _Float16 Bsh[128*64];

  int tid = threadIdx.x, lane = tid & 63, w = tid >> 6;
  int wm = w & 1, wn = w >> 1;

  // staging: slot s = lane&7 of row-group fetches global chunk kc = s ^ (r&7)
  int kc = ((lane & 7) ^ ((lane >> 3) & 7)) * 8;
  const _Float16* aptr[4];
  const _Float16* bptr[4];
  #pragma unroll
  for (int i = 0; i < 4; ++i) {
    int r = (w*4 + i)*8 + (lane >> 3);
    int rg = tile*128 + r;
    size_t arow;
    if (G1) arow = (g < 8) ? (size_t)slot_src[g*CAP + rg] : (size_t)rg;
    else    arow = (size_t)(slot_base + rg);
    aptr[i] = A0 + arow * (size_t)K + kc;
    bptr[i] = Bw + (size_t)(n0 + r) * K + kc;
  }

  f32x16 acc[2][2];
  #pragma unroll
  for (int mi = 0; mi < 2; ++mi)
    #pragma unroll
    for (int ni = 0; ni < 2; ++ni)
      acc[mi][ni] = (f32x16)0.0f;

  for (int k0 = 0; k0 < K; k0 += 64) {
    #pragma unroll
    for (int i = 0; i < 4; ++i) load_lds16(aptr[i] + k0, &Ash[(w*4+i)*512]);
    #pragma unroll
    for (int i = 0; i < 4; ++i) load_lds16(bptr[i] + k0, &Bsh[(w*4+i)*512]);
    __syncthreads();
    #pragma unroll
    for (int ks = 0; ks < 4; ++ks) {           // k = 16 per step
      int chunk = ks*2 + (lane >> 5);          // 16B chunk holding this lane's 8 k-vals
      f16x8 af[2], bf[2];
      #pragma unroll
      for (int mi = 0; mi < 2; ++mi) {
        int row = wm*64 + mi*32 + (lane & 31);
        af[mi] = *(const f16x8*)&Ash[row*64 + (chunk ^ (row & 7))*8];
      }
      #pragma unroll
      for (int ni = 0; ni < 2; ++ni) {
        int row = wn*64 + ni*32 + (lane & 31);
        bf[ni] = *(const f16x8*)&Bsh[row*64 + (chunk ^ (row & 7))*8];
      }
      #pragma unroll
      for (int mi = 0; mi < 2; ++mi)
        #pragma unroll
        for (int ni = 0; ni < 2; ++ni)
          acc[mi][ni] = __builtin_amdgcn_mfma_f32_32x32x16_f16(af[mi], bf[ni], acc[mi][ni], 0, 0, 0);
    }
    __syncthreads();
  }

  // epilogue: 32x32 C/D layout col=lane&31, row=(reg&3)+8*(reg>>2)+4*(lane>>5)  (m74/m101)
  #pragma unroll
  for (int mi = 0; mi < 2; ++mi) {
    #pragma unroll
    for (int reg = 0; reg < 16; ++reg) {
      int m = wm*64 + mi*32 + (reg & 3) + 8*(reg >> 2) + 4*(lane >> 5);
      int rg = tile*128 + m;
      if (rg < rows) {
        size_t orow = (size_t)(slot_base + rg);
        #pragma unroll
        for (int ni = 0; ni < 2; ++ni) {
          int n = n0 + wn*64 + ni*32 + (lane & 31);
          float v = acc[mi][ni][reg] + bias[n];
          if (G1) v = v / (1.0f + __expf(-v));   // SiLU
          Out[orow * (size_t)NOUT + n] = (_Float16)v;
        }
      }
    }
  }
}

// ---------------- 7) combine: y = g1*e1out + g2*e2out + 0.1*shared -------------
__global__ __launch_bounds__(256) void combine_kernel(const int4* __restrict__ meta_i,
    const f32x2* __restrict__ meta_f, const _Float16* __restrict__ out16,
    float* __restrict__ out)
{
  int n = blockIdx.x;
  int h = threadIdx.x * 4;
  int4 mi = meta_i[n];
  f32x2 mf = meta_f[n];
  f16x4 sv = *(const f16x4*)(out16 + (size_t)(NSLOT + n)*HD + h);
  f32x4 y;
  #pragma unroll
  for (int j = 0; j < 4; ++j) y[j] = 0.1f * (float)sv[j];
  if (mi.y >= 0) {
    f16x4 v = *(const f16x4*)(out16 + (size_t)(mi.x*CAP + mi.y)*HD + h);
    #pragma unroll
    for (int j = 0; j < 4; ++j) y[j] += mf[0] * (float)v[j];
  }
  if (mi.w >= 0) {
    f16x4 v = *(const f16x4*)(out16 + (size_t)(mi.z*CAP + mi.w)*HD + h);
    #pragma unroll
    for (int j = 0; j < 4; ++j) y[j] += mf[1] * (float)v[j];
  }
  *(f32x4*)(out + (size_t)n*HD + h) = y;
}

__global__ void fill_sentinel(float* out, int nelem) {
  int i = blockIdx.x*256 + threadIdx.x;
  if (i < nelem) out[i] = 12345.0f;   // distinctive: means ws_size was too small
}

// ---------------- host ----------------
extern "C" void kernel_launch(void* const* d_in, const int* in_sizes, int n_in,
                              void* d_out, int out_size, void* d_ws, size_t ws_size,
                              hipStream_t stream) {
  const float* x   = (const float*)d_in[0];
  const float* rw  = (const float*)d_in[1];
  const float* w1  = (const float*)d_in[2];
  const float* b1  = (const float*)d_in[3];
  const float* w2  = (const float*)d_in[4];
  const float* b2  = (const float*)d_in[5];
  const float* sw1 = (const float*)d_in[6];
  const float* sb1 = (const float*)d_in[7];
  const float* sw2 = (const float*)d_in[8];
  const float* sb2 = (const float*)d_in[9];
  float* out = (float*)d_out;

  char* p = (char*)d_ws;
  auto alloc = [&](size_t bytes) { char* r = p; p += (bytes + 255) & ~(size_t)255; return r; };
  _Float16* x16  = (_Float16*)alloc((size_t)NTOK*HD*2);
  _Float16* w1t  = (_Float16*)alloc((size_t)NE*FD*HD*2);
  _Float16* w2t  = (_Float16*)alloc((size_t)NE*HD*FD*2);
  _Float16* sw1t = (_Float16*)alloc((size_t)FD*HD*2);
  _Float16* sw2t = (_Float16*)alloc((size_t)HD*FD*2);
  _Float16* mid  = (_Float16*)alloc((size_t)TOTSLOT*FD*2);
  _Float16* o16  = (_Float16*)alloc((size_t)TOTSLOT*HD*2);
  double* logits = (double*)alloc((size_t)NTOK*NE*8);
  int4*   meta_i = (int4*)alloc((size_t)NTOK*16);
  f32x2*  meta_f = (f32x2*)alloc((size_t)NTOK*8);
  int* slot_src  = (int*)alloc((size_t)NSLOT*4);
  int* rows_dev  = (int*)alloc(64);
  size_t need = (size_t)(p - (char*)d_ws);
  if (need > ws_size) {
    fill_sentinel<<<(out_size+255)/256, 256, 0, stream>>>(out, out_size);
    return;
  }

  transpose_cvt<<<4864, 512, 0, stream>>>(w1, w2, sw1, sw2, x, w1t, w2t, sw1t, sw2t, x16);
  router_kernel<<<NTOK/4, 256, 0, stream>>>(x, rw, logits);
  gating_kernel<<<1, 1024, 0, stream>>>(logits, meta_i, meta_f, slot_src, rows_dev);
  gemm_kernel<HD, FD, true><<<112*(FD/128), 256, 0, stream>>>(
      x16, w1t, sw1t, b1, sb1, mid, slot_src, rows_dev);
  gemm_kernel<FD, HD, false><<<112*(HD/128), 256, 0, stream>>>(
      mid, w2t, sw2t, b2, sb2, o16, slot_src, rows_dev);
  combine_kernel<<<NTOK, 256, 0, stream>>>(meta_i, meta_f, o16, out);
}